// Round 13
// baseline (152.110 us; speedup 1.0000x reference)
//
#include <hip/hip_runtime.h>
#include <math.h>

// M=512, N=1024, G=16, D=64, C=1024. All GEMM-shaped work on bf16 MFMA 16x16x32.
// pos_bias uses a bf16 hi/lo split MFMA (rounds 4/6: plain bf16 dot error
// ~2e-4 sign-flips entries in log-clip floor rows -> absmax 0.205).
//
// Round 13: dispatch-order + overlap restructure. Measured totals exceed
// kernel sums by a fixed ~95us (harness restore/poison inside timed window);
// remaining controllable time is ~50us of kernels. Two fixes:
//  (a) pos has no dependency on the casts -> moved AFTER projvt, merged into
//      the same launch (flat grid: 768 projvt blocks + 4096 pos blocks).
//      MFMA-bound projvt and VALU-bound pos co-schedule (m114: time~max).
//  (b) bias planes are now written at the tail of launch2, immediately before
//      attn reads them -> L2-resident (r8-r12: attn FETCH 41.7MB = HBM bias).
//
// Pipeline (3 launches): cast -> projvt+pos -> attn_out.
//
// qk_pack[g][p][part][lane][8shorts]: X[row][col], row=p*16+(lane&15),
// col=part*32+(lane>>4)*8+j (g-slice base g*64); p: q rows p=row>>4 (0..31),
// k rows 32+(row-512)>>4 (32..95). vt_pack[g][cc][p][part][lane][8]: p=o>>4.
//
// Workspace (float offsets), total 12,320,768 floats = 49.3 MB:
//   [0,1572864)        : shorts: in_bf (feat 524288 + ctx 1048576), qk_pack (1572864)
//   [1572864,5767168)  : bias_gt  fp16 (16,512,1024)
//   [5767168,9961472)  : bias_ctx fp16 (16,1024,512)
//   [9961472,10485760) : wconv_bf (1048576 s)
//   [10485760,11272192): vt_pack (1572864 s)
//   [11272192,12320768): wfcgt_bf + wfcctx_bf

typedef __attribute__((ext_vector_type(8))) short short8;   // 8 bf16 = 4 VGPRs
typedef __attribute__((ext_vector_type(4))) float floatx4;
typedef __attribute__((ext_vector_type(4))) _Float16 half4;
typedef __attribute__((ext_vector_type(4))) unsigned uint4v;

__device__ inline unsigned short f32_bf16_rne(float x) {
    union { float f; unsigned u; } v; v.f = x;
    unsigned u = v.u;
    return (unsigned short)((u + 0x7fffu + ((u >> 16) & 1u)) >> 16);
}

__device__ inline unsigned fbits(float x) {
    union { float f; unsigned u; } v; v.f = x; return v.u;
}
__device__ inline float bitsf(unsigned u) {
    union { unsigned u; float f; } v; v.u = u; return v.f;
}

__device__ __forceinline__ floatx4 mfma16(short8 a, short8 b, floatx4 c) {
    return __builtin_amdgcn_mfma_f32_16x16x32_bf16(a, b, c, 0, 0, 0);
}

// ---------------------------------------------------------------------------
// 64x64 tile NT bf16 GEMM core with FRAGMENT-PACKED output (r10, verified).
// ---------------------------------------------------------------------------
__device__ __forceinline__ void gemm_tile_pack(
    const unsigned short* __restrict__ Ab, int lda,
    const unsigned short* __restrict__ Bb, int ldb, int K,
    unsigned short* __restrict__ out_base,
    const float* __restrict__ biasvec,
    unsigned short* As, unsigned short* Bs)
{
    const int tid = threadIdx.x;
    const int lr = tid >> 3;          // 0..31 (8 lanes/row)
    const int lk = (tid & 7) * 8;     // 0..56
    const int lane = tid & 63;
    const int wave = tid >> 6;
    const int qr = (wave >> 1) * 32;
    const int qc = (wave & 1) * 32;
    const int m = lane & 15;
    const int quad = lane >> 4;

    const unsigned short* Ap  = Ab + (long long)lr * lda + lk;
    const unsigned short* Ap2 = Ap + 32LL * lda;
    const unsigned short* Bp  = Bb + (long long)lr * ldb + lk;
    const unsigned short* Bp2 = Bp + 32LL * ldb;
    unsigned short* AsW  = As + lr * 72 + lk;
    unsigned short* AsW2 = As + (lr + 32) * 72 + lk;
    unsigned short* BsW  = Bs + lr * 72 + lk;
    unsigned short* BsW2 = Bs + (lr + 32) * 72 + lk;
    const unsigned short* a0p = As + (qr + m) * 72 + quad * 8;
    const unsigned short* b0p = Bs + (qc + m) * 72 + quad * 8;

    floatx4 acc00 = {0.f,0.f,0.f,0.f}, acc01 = {0.f,0.f,0.f,0.f};
    floatx4 acc10 = {0.f,0.f,0.f,0.f}, acc11 = {0.f,0.f,0.f,0.f};

    int4 pa0 = *(const int4*)Ap;
    int4 pa1 = *(const int4*)Ap2;
    int4 pb0 = *(const int4*)Bp;
    int4 pb1 = *(const int4*)Bp2;
    int4 qa0 = *(const int4*)(Ap + 64);
    int4 qa1 = *(const int4*)(Ap2 + 64);
    int4 qb0 = *(const int4*)(Bp + 64);
    int4 qb1 = *(const int4*)(Bp2 + 64);

    for (int k0 = 0; ; ) {
        __syncthreads();
        *(int4*)AsW  = pa0;
        *(int4*)AsW2 = pa1;
        *(int4*)BsW  = pb0;
        *(int4*)BsW2 = pb1;
        __syncthreads();
        pa0 = qa0; pa1 = qa1; pb0 = qb0; pb1 = qb1;
        const int kf = k0 + 128;
        if (kf < K) {
            qa0 = *(const int4*)(Ap + kf);
            qa1 = *(const int4*)(Ap2 + kf);
            qb0 = *(const int4*)(Bp + kf);
            qb1 = *(const int4*)(Bp2 + kf);
        }
        #pragma unroll
        for (int kk = 0; kk < 64; kk += 32) {
            short8 a0 = *(const short8*)(a0p + kk);
            short8 a1 = *(const short8*)(a0p + 16 * 72 + kk);
            short8 b0 = *(const short8*)(b0p + kk);
            short8 b1 = *(const short8*)(b0p + 16 * 72 + kk);
            acc00 = mfma16(a0, b0, acc00);
            acc01 = mfma16(a0, b1, acc01);
            acc10 = mfma16(a1, b0, acc10);
            acc11 = mfma16(a1, b1, acc11);
        }
        k0 += 64;
        if (k0 >= K) break;
    }

    float bias0 = 0.f, bias1 = 0.f;
    if (biasvec) { bias0 = biasvec[qc + m]; bias1 = biasvec[qc + 16 + m]; }

    __syncthreads();
    const floatx4 accs[2][2] = { {acc00, acc01}, {acc10, acc11} };
    #pragma unroll
    for (int i = 0; i < 2; ++i)
        #pragma unroll
        for (int r = 0; r < 4; ++r) {
            const int lrow = qr + i * 16 + quad * 4 + r;
            #pragma unroll
            for (int j = 0; j < 2; ++j) {
                const int lcol = qc + j * 16 + m;
                float val = accs[i][j][r] + (j ? bias1 : bias0);
                As[lrow * 72 + lcol] = f32_bf16_rne(val);
            }
        }
    __syncthreads();
    #pragma unroll
    for (int h = 0; h < 2; ++h) {
        const int f = h * 2048 + tid * 8;
        const int lanep = (f >> 3) & 63;
        const int part = (f >> 9) & 1;
        const int ploc = f >> 10;
        const int row = ploc * 16 + (lanep & 15);
        const int col = part * 32 + ((lanep >> 4) << 3);
        short8 v8 = *(const short8*)&As[row * 72 + col];
        *(short8*)(out_base + f) = v8;
    }
}

// ---------------------------------------------------------------------------
// fp32 -> bf16 casts (5 tensors).
// ---------------------------------------------------------------------------
__global__ __launch_bounds__(256) void cast_kernel(
    const float* s0, unsigned short* d0, int n0,
    const float* s1, unsigned short* d1, int n1,
    const float* s2, unsigned short* d2, int n2,
    const float* s3, unsigned short* d3, int n3,
    const float* s4, unsigned short* d4, int n4)
{
    const float* s; unsigned short* d; int n;
    switch (blockIdx.y) {
        case 0: s = s0; d = d0; n = n0; break;
        case 1: s = s1; d = d1; n = n1; break;
        case 2: s = s2; d = d2; n = n2; break;
        case 3: s = s3; d = d3; n = n3; break;
        default: s = s4; d = d4; n = n4; break;
    }
    int idx = (blockIdx.x * 256 + threadIdx.x) * 4;
    if (idx < n) {
        float4 v = *(const float4*)(s + idx);
        ushort4 o;
        o.x = f32_bf16_rne(v.x); o.y = f32_bf16_rne(v.y);
        o.z = f32_bf16_rne(v.z); o.w = f32_bf16_rne(v.w);
        *(ushort4*)(d + idx) = o;
    }
}

// ---------------------------------------------------------------------------
// Merged projvt + pos, flat grid 4864 blocks:
//   [0,384)    proj: qk rows [feat;ctx] @ w_fc^T + b -> qk_pack
//   [384,768)  vt  : vt[g][o][c] -> vt_pack
//   [768,4864) pos : 256 pairs/block, phase A/B (r12-verified body) -> fp16 bias
// pos runs last in dispatch order -> bias written right before attn (L2-warm);
// MFMA-bound projvt overlaps VALU-bound pos across waves (m114).
// ---------------------------------------------------------------------------
__global__ __launch_bounds__(256) void projvt_pos_kernel(
    const unsigned short* __restrict__ in_bf, const unsigned short* __restrict__ wgt,
    const unsigned short* __restrict__ wctx,
    const float* __restrict__ bgt, const float* __restrict__ bctx,
    unsigned short* __restrict__ qk_pack,
    const unsigned short* __restrict__ wconv, unsigned short* __restrict__ vt_pack,
    const float* __restrict__ box, const float* __restrict__ ctx_box,
    const float* __restrict__ w_gt, const float* __restrict__ b_gt,
    const float* __restrict__ w_ctx, const float* __restrict__ b_ctx,
    _Float16* __restrict__ bias_gt, _Float16* __restrict__ bias_ctx)
{
    __shared__ __align__(16) unsigned char smem[64 * 72 * 2 * 2];   // 36864 B union
    const int bxf = blockIdx.x;

    if (bxf < 768) {
        unsigned short* As = (unsigned short*)smem;
        unsigned short* Bs = As + 64 * 72;
        if (bxf < 384) {
            const int x = bxf % 24, g = bxf / 24;
            const int bm = x * 64;
            const unsigned short* B = (bm < 512) ? wgt : wctx;
            const float* bias = (bm < 512) ? bgt : bctx;
            gemm_tile_pack(in_bf + (long long)bm * 1024, 1024,
                           B + (long long)g * 65536, 1024, 1024,
                           qk_pack + ((long long)g * 96 + x * 4) * 1024,
                           bias + g * 64, As, Bs);
        } else {
            const int b2 = bxf - 384;
            const int cc = b2 % 24, g = b2 / 24;
            gemm_tile_pack(wconv + (long long)g * 65536, 1024,
                           in_bf + (long long)cc * 65536, 1024, 1024,
                           vt_pack + ((long long)g * 24 + cc) * 4096,
                           nullptr, As, Bs);
        }
        return;
    }

    // -------- pos branch: 256 pairs per block (r12-verified body)
    const int bx = bxf - 768;            // 0..4095
    const bool first = (bx < 2048);
    const long long blk = first ? bx : (bx - 2048);
    const float* boxA = first ? box : ctx_box;
    const float* boxB = first ? ctx_box : box;
    const float* w_pos = first ? w_gt : w_ctx;
    const float* b_pos = first ? b_gt : b_ctx;
    _Float16* out = first ? bias_gt : bias_ctx;
    const int shift = first ? 10 : 9;

    unsigned short* BsH = (unsigned short*)smem;            // 16*72 = 2304 B
    unsigned short* BsL = BsH + 16 * 72;                    // 2304 B
    float* posL = (float*)(smem + 4608);                    // 4*68*4 = 1088 B
    _Float16* stg = (_Float16*)(smem + 5696);               // 16*68*2 = 2176 B

    const int tid = threadIdx.x;

    {   // stage B: w_pos (16x64 fp32) -> bf16 hi + lo (trunc split, packed)
        const int g = tid >> 4;
        const int d = (tid & 15) * 4;
        float4 wv = *(const float4*)(w_pos + g * 64 + d);
        unsigned u0 = fbits(wv.x), u1 = fbits(wv.y);
        unsigned u2 = fbits(wv.z), u3 = fbits(wv.w);
        unsigned r0 = fbits(wv.x - bitsf(u0 & 0xFFFF0000u));
        unsigned r1 = fbits(wv.y - bitsf(u1 & 0xFFFF0000u));
        unsigned r2 = fbits(wv.z - bitsf(u2 & 0xFFFF0000u));
        unsigned r3 = fbits(wv.w - bitsf(u3 & 0xFFFF0000u));
        uint2 hv, lv;
        hv.x = (u0 >> 16) | (u1 & 0xFFFF0000u);
        hv.y = (u2 >> 16) | (u3 & 0xFFFF0000u);
        lv.x = (r0 >> 16) | (r1 & 0xFFFF0000u);
        lv.y = (r2 >> 16) | (r3 & 0xFFFF0000u);
        *(uint2*)&BsH[g * 72 + d] = hv;
        *(uint2*)&BsL[g * 72 + d] = lv;
    }
    __syncthreads();

    const int lane = tid & 63;
    const int w = tid >> 6;
    const int m = lane & 15;
    const int quad = lane >> 4;
    const bool qlow = (quad < 2);
    const float phase = (quad & 1) ? 1.57079632679f : 0.0f;  // cos(t)=sin(t+pi/2)
    const float bpv = b_pos[m];

    const unsigned short* bpH = &BsH[m * 72 + quad * 8];
    const unsigned short* bpL = &BsL[m * 72 + quad * 8];
    short8 bH0 = *(const short8*)bpH;
    short8 bH1 = *(const short8*)(bpH + 32);
    short8 bL0 = *(const short8*)bpL;
    short8 bL1 = *(const short8*)(bpL + 32);

    const float w100[8] = {100.f, 42.169650342f, 17.782794100f, 7.498942093f,
                           3.162277660f, 1.333521432f, 0.562341325f, 0.237137371f};
    const long long pbase = blk * 256;

    for (int it = 0; it < 4; ++it) {
        const long long pb = pbase + it * 64;

        // ---- phase A: each pos component computed once (thread (pl, p))
        {
            const int pl = tid & 63;
            const int p = tid >> 6;      // wave-uniform
            const long long pair = pb + pl;
            const int i = (int)(pair >> shift);
            const int j = (int)(pair & ((1 << shift) - 1));
            float4 ba = *(const float4*)(boxA + i * 4);
            float4 bb = *(const float4*)(boxB + j * 4);
            float posv;
            if (p == 0) {
                float r = __builtin_amdgcn_rcpf(ba.z - ba.x + 1.f);
                posv = __logf(fmaxf(fabsf((0.5f*(ba.x+ba.z) - 0.5f*(bb.x+bb.z)) * r), 1e-3f));
            } else if (p == 1) {
                float r = __builtin_amdgcn_rcpf(ba.w - ba.y + 1.f);
                posv = __logf(fmaxf(fabsf((0.5f*(ba.y+ba.w) - 0.5f*(bb.y+bb.w)) * r), 1e-3f));
            } else if (p == 2) {
                float r = __builtin_amdgcn_rcpf(ba.z - ba.x + 1.f);
                posv = __logf((bb.z - bb.x + 1.f) * r);
            } else {
                float r = __builtin_amdgcn_rcpf(ba.w - ba.y + 1.f);
                posv = __logf((bb.w - bb.y + 1.f) * r);
            }
            posL[p * 68 + pl] = posv;
        }
        __syncthreads();

        // ---- phase B: A-fragments in registers from posL
        const int plB = w * 16 + m;
        const float pos_lo = posL[(qlow ? 0 : 1) * 68 + plB];
        const float pos_hi = posL[(qlow ? 2 : 3) * 68 + plB];

        unsigned hp0[4], lp0[4], hp1[4], lp1[4];
        #pragma unroll
        for (int fi = 0; fi < 4; ++fi) {
            float x0 = fmaxf(__sinf(fmaf(w100[2*fi],     pos_lo, phase)), 0.f);
            float x1 = fmaxf(__sinf(fmaf(w100[2*fi + 1], pos_lo, phase)), 0.f);
            unsigned u0 = fbits(x0), u1 = fbits(x1);
            unsigned r0 = fbits(x0 - bitsf(u0 & 0xFFFF0000u));
            unsigned r1 = fbits(x1 - bitsf(u1 & 0xFFFF0000u));
            hp0[fi] = (u0 >> 16) | (u1 & 0xFFFF0000u);
            lp0[fi] = (r0 >> 16) | (r1 & 0xFFFF0000u);
            float y0 = fmaxf(__sinf(fmaf(w100[2*fi],     pos_hi, phase)), 0.f);
            float y1 = fmaxf(__sinf(fmaf(w100[2*fi + 1], pos_hi, phase)), 0.f);
            unsigned v0 = fbits(y0), v1 = fbits(y1);
            unsigned s0r = fbits(y0 - bitsf(v0 & 0xFFFF0000u));
            unsigned s1r = fbits(y1 - bitsf(v1 & 0xFFFF0000u));
            hp1[fi] = (v0 >> 16) | (v1 & 0xFFFF0000u);
            lp1[fi] = (s0r >> 16) | (s1r & 0xFFFF0000u);
        }
        union { uint4v u; short8 s; } cH0, cL0, cH1, cL1;
        cH0.u = (uint4v){hp0[0], hp0[1], hp0[2], hp0[3]};
        cL0.u = (uint4v){lp0[0], lp0[1], lp0[2], lp0[3]};
        cH1.u = (uint4v){hp1[0], hp1[1], hp1[2], hp1[3]};
        cL1.u = (uint4v){lp1[0], lp1[1], lp1[2], lp1[3]};

        floatx4 acc = {0.f, 0.f, 0.f, 0.f};
        acc = mfma16(cH0.s, bH0, acc);
        acc = mfma16(cH1.s, bH1, acc);
        acc = mfma16(cH0.s, bL0, acc);
        acc = mfma16(cH1.s, bL1, acc);
        acc = mfma16(cL0.s, bH0, acc);
        acc = mfma16(cL1.s, bH1, acc);

        // C: row = pair-local w*16 + quad*4 + r, col = group m
        #pragma unroll
        for (int r = 0; r < 4; ++r)
            stg[m * 68 + w * 16 + quad * 4 + r] =
                (_Float16)__logf(fmaxf(acc[r] + bpv, 1e-6f));
        __syncthreads();   // stg ready; posL reads of this chunk complete

        const int g2 = tid >> 4, c16 = tid & 15;
        *(half4*)(out + (long long)g2 * 524288 + pb + c16 * 4) =
            *(const half4*)&stg[g2 * 68 + c16 * 4];
        // next phase A writes posL (not stg) -> safe; next stg write is after
        // the next barrier -> store reads above are protected.
    }
}

// ---------------------------------------------------------------------------
// Fused scores + bias + softmax + output GEMM (r10, verified).
// ---------------------------------------------------------------------------
template <int NC>
__device__ __forceinline__ void attn_body(
    int g, int bx,
    const unsigned short* __restrict__ qk, int pA, int pB0,
    const _Float16* __restrict__ bias,
    const unsigned short* __restrict__ vt, int cc0,
    const float* __restrict__ b_conv, float* __restrict__ outp,
    unsigned short* wpack, float* redA, float* redB)
{
    constexpr int NCOL = NC * 64;
    constexpr int WS = NCOL + 8;
    constexpr int SHIFT = (NC == 16) ? 10 : 9;

    const int bm = bx * 16;
    const int tid = threadIdx.x;
    const int lane = tid & 63;
    const int w = tid >> 6;
    const int m = lane & 15;
    const int quad = lane >> 4;

    _Float16* bb = (_Float16*)wpack;
    {
        const _Float16* bsrc = bias + (long long)g * 524288 + (long long)bm * NCOL;
        #pragma unroll
        for (int i = 0; i < (16 * NCOL) / (256 * 8); ++i) {
            const int idx = (i * 256 + tid) * 8;
            const int row = idx >> SHIFT;
            const int col = idx & (NCOL - 1);
            *(int4*)(bb + row * WS + col) = *(const int4*)(bsrc + idx);
        }
    }

    const unsigned short* abase = qk + ((long long)(g * 96 + pA)) * 1024;
    short8 aq0 = *(const short8*)(abase + lane * 8);
    short8 aq1 = *(const short8*)(abase + 512 + lane * 8);

    const unsigned short* bptr = qk + ((long long)(g * 96 + pB0 + w)) * 1024 + lane * 8;
    short8 B0[2], B1[2];
    B0[0] = *(const short8*)bptr;
    B1[0] = *(const short8*)(bptr + 512);
    B0[1] = *(const short8*)(bptr + 4096);
    B1[1] = *(const short8*)(bptr + 4096 + 512);

    __syncthreads();   // bias staged

    const _Float16* brow = bb + (quad * 4) * WS + w * 16 + m;

    float v[NC][4];
    #pragma unroll
    for (int c = 0; c < NC; ++c) {
        float bv[4];
        #pragma unroll
        for (int r = 0; r < 4; ++r)
            bv[r] = (float)brow[r * WS + c * 64];
        floatx4 acc = {0.f, 0.f, 0.f, 0.f};
        acc = mfma16(aq0, B0[c & 1], acc);
        acc = mfma16(aq1, B1[c & 1], acc);
        if (c + 2 < NC) {
            const unsigned short* nb = bptr + (long long)(c + 2) * 4096;
            B0[c & 1] = *(const short8*)nb;
            B1[c & 1] = *(const short8*)(nb + 512);
        }
        #pragma unroll
        for (int r = 0; r < 4; ++r)
            v[c][r] = fmaf(0.125f, acc[r], bv[r]);
    }

    const unsigned short* vptr = vt + ((long long)(g * 24 + cc0)) * 4096
                               + w * 1024 + lane * 8;
    short8 V0[2], V1[2];
    V0[0] = *(const short8*)vptr;
    V1[0] = *(const short8*)(vptr + 512);
    V0[1] = *(const short8*)(vptr + 4096);
    V1[1] = *(const short8*)(vptr + 4096 + 512);

    float rmax[4];
    #pragma unroll
    for (int r = 0; r < 4; ++r) {
        float mx = v[0][r];
        #pragma unroll
        for (int c = 1; c < NC; ++c) mx = fmaxf(mx, v[c][r]);
        #pragma unroll
        for (int off = 1; off < 16; off <<= 1)
            mx = fmaxf(mx, __shfl_xor(mx, off, 64));
        rmax[r] = mx;
    }
    if (m == 0) {
        #pragma unroll
        for (int r = 0; r < 4; ++r) redA[w * 16 + quad * 4 + r] = rmax[r];
    }
    __syncthreads();
    #pragma unroll
    for (int r = 0; r < 4; ++r)
        rmax[r] = fmaxf(fmaxf(redA[quad*4+r], redA[16 + quad*4+r]),
                        fmaxf(redA[32 + quad*4+r], redA[48 + quad*4+r]));

    float rsum[4] = {0.f, 0.f, 0.f, 0.f};
    #pragma unroll
    for (int c = 0; c < NC; ++c)
        #pragma unroll
        for (int r = 0; r < 4; ++r) {
            v[c][r] = __expf(v[c][r] - rmax[r]);
            rsum[r] += v[c][r];
        }
    #pragma unroll
    for (int r = 0; r < 4; ++r)
        #pragma unroll
        for (int off = 1; off < 16; off <<= 1)
            rsum[r] += __shfl_xor(rsum[r], off, 64);
    if (m == 0) {
        #pragma unroll
        for (int r = 0; r < 4; ++r) redB[w * 16 + quad * 4 + r] = rsum[r];
    }
    __syncthreads();   // all bias reads complete before wpack overwrite
    float rinv[4];
    #pragma unroll
    for (int r = 0; r < 4; ++r)
        rinv[r] = 1.f / (redB[quad*4+r] + redB[16 + quad*4+r] +
                         redB[32 + quad*4+r] + redB[48 + quad*4+r]);

    #pragma unroll
    for (int c = 0; c < NC; ++c)
        #pragma unroll
        for (int r = 0; r < 4; ++r)
            wpack[(quad * 4 + r) * WS + c * 64 + w * 16 + m] =
                f32_bf16_rne(v[c][r] * rinv[r]);

    __syncthreads();   // wpack visible

    floatx4 oacc = {0.f, 0.f, 0.f, 0.f};
    const unsigned short* awp = wpack + m * WS + quad * 8;
    #pragma unroll
    for (int kc = 0; kc < NC; ++kc) {
        short8 a0 = *(const short8*)(awp + kc * 64);
        short8 a1 = *(const short8*)(awp + kc * 64 + 32);
        oacc = mfma16(a0, V0[kc & 1], oacc);
        oacc = mfma16(a1, V1[kc & 1], oacc);
        if (kc + 2 < NC) {
            const unsigned short* nv = vptr + (long long)(kc + 2) * 4096;
            V0[kc & 1] = *(const short8*)nv;
            V1[kc & 1] = *(const short8*)(nv + 512);
        }
    }

    const int o = w * 16 + m;
    const float bc = b_conv[g * 64 + o];
    __syncthreads();   // wpack weight reads done
    float* ot = (float*)wpack;         // 16 x 68 floats
    #pragma unroll
    for (int r = 0; r < 4; ++r)
        ot[(quad * 4 + r) * 68 + o] = oacc[r] + bc;
    __syncthreads();
    const int orow = tid >> 4, oc4 = (tid & 15) * 4;
    float4 ov = *(const float4*)&ot[orow * 68 + oc4];
    *(float4*)(outp + (long long)(bm + orow) * 1024 + g * 64 + oc4) = ov;
}

__global__ __launch_bounds__(256) void attn_out_kernel(
    const unsigned short* __restrict__ qk_pack,
    const _Float16* __restrict__ bias_gt, const _Float16* __restrict__ bias_ctx,
    const unsigned short* __restrict__ vt_pack, const float* __restrict__ b_conv,
    float* __restrict__ out_gt, float* __restrict__ out_ctx)
{
    __shared__ __align__(16) unsigned short wpack[16 * 1032];
    __shared__ float redA[64], redB[64];

    const int bx = blockIdx.x;
    if (bx < 512) {
        const int rb = bx & 31;
        attn_body<16>(bx >> 5, rb, qk_pack, /*pA=*/rb, /*pB0=*/32,
                      bias_gt, vt_pack, /*cc0=*/8, b_conv, out_gt,
                      wpack, redA, redB);
    } else {
        const int b2 = bx - 512;
        const int rb = b2 & 63;
        attn_body<8>(b2 >> 6, rb, qk_pack, /*pA=*/32 + rb, /*pB0=*/0,
                     bias_ctx, vt_pack, /*cc0=*/0, b_conv, out_ctx,
                     wpack, redA, redB);
    }
}

// ---------------------------------------------------------------------------
extern "C" void kernel_launch(void* const* d_in, const int* in_sizes, int n_in,
                              void* d_out, int out_size, void* d_ws, size_t ws_size,
                              hipStream_t stream)
{
    const float* feat     = (const float*)d_in[0];
    const float* ctx_feat = (const float*)d_in[1];
    const float* box      = (const float*)d_in[2];
    const float* ctx_box  = (const float*)d_in[3];
    const float* w_fc_gt  = (const float*)d_in[4];
    const float* b_fc_gt  = (const float*)d_in[5];
    const float* w_fc_ctx = (const float*)d_in[6];
    const float* b_fc_ctx = (const float*)d_in[7];
    const float* w_pos_gt = (const float*)d_in[8];
    const float* b_pos_gt = (const float*)d_in[9];
    const float* w_pos_ctx= (const float*)d_in[10];
    const float* b_pos_ctx= (const float*)d_in[11];
    const float* w_conv   = (const float*)d_in[12];
    const float* b_conv   = (const float*)d_in[13];

    float* ws = (float*)d_ws;
    unsigned short* in_bf   = (unsigned short*)ws;           // 1572864 s
    unsigned short* ctx_bf  = in_bf + 524288LL;
    unsigned short* qk_pack = in_bf + 1572864LL;             // 1572864 s
    _Float16* bias_gt  = (_Float16*)(ws + 1572864LL);        // 8388608 h
    _Float16* bias_ctx = (_Float16*)(ws + 5767168LL);        // 8388608 h
    unsigned short* wconv_bf = (unsigned short*)(ws + 9961472LL);   // 1048576 s
    unsigned short* vt_pack  = (unsigned short*)(ws + 10485760LL);  // 1572864 s
    unsigned short* wfcgt_bf = (unsigned short*)(ws + 11272192LL);  // 1048576 s
    unsigned short* wfcctx_bf= wfcgt_bf + 1048576LL;                // 1048576 s

    float* out_gt  = (float*)d_out;
    float* out_ctx = (float*)d_out + 524288LL;

    // 1) casts
    hipLaunchKernelGGL(cast_kernel, dim3(1024, 5), dim3(256), 0, stream,
                       feat, in_bf, 524288,
                       ctx_feat, ctx_bf, 1048576,
                       w_fc_gt, wfcgt_bf, 1048576,
                       w_fc_ctx, wfcctx_bf, 1048576,
                       w_conv, wconv_bf, 1048576);

    // 2) merged projvt + pos (pos blocks last -> bias L2-warm for attn)
    hipLaunchKernelGGL(projvt_pos_kernel, dim3(4864), dim3(256), 0, stream,
                       in_bf, wfcgt_bf, wfcctx_bf, b_fc_gt, b_fc_ctx, qk_pack,
                       wconv_bf, vt_pack,
                       box, ctx_box, w_pos_gt, b_pos_gt, w_pos_ctx, b_pos_ctx,
                       bias_gt, bias_ctx);

    // 3) fused scores+softmax+output, both directions
    hipLaunchKernelGGL(attn_out_kernel, dim3(1536), dim3(256), 0, stream,
                       qk_pack, bias_gt, bias_ctx, vt_pack, b_conv, out_gt, out_ctx);
}